// Round 3
// baseline (232.969 us; speedup 1.0000x reference)
//
#include <hip/hip_runtime.h>

// YOLO loss, forward only. pred/target: (16384, 7, 7, 30) fp32, out: scalar fp32.
// S=7, B=2, CLS=20, N=30, LAMBDA_COORD=5, LAMBDA_NOOBJ=0.5, BATCH=16384.
// NOTE: reference conf_loc = arange(B)*B+4 = [4,6] (not [4,9]) — mirrored here.
//
// R4: barrier-free per-wave pipeline. History:
//   R1 register-direct 120B-stride: 75us (request-serialization, 22% HBM)
//   R2 global_load_lds DMA, 1 wave/blk: 75us (DMA completion ~2.1 B/cyc/wave)
//   R3 reg-staged + LDS + barrier: 73.5us (phase-structured: memory idle
//      during write/barrier/compute/retire -> ~40% memory duty cycle;
//      delivered 4.3 B/cyc/CU vs 10.25 HBM share. No counter saturated.)
// R4 keeps R3's proven coalesced reg-staging but removes ALL main-loop
// barriers: persistent waves, each wave owns a private 15360 B LDS slice and
// pipelines  store_tile(t) -> prefetch(t+STRIDE) -> compute(t).  The prefetch
// is in flight across the whole compute phase of every iteration on every
// wave -> continuous memory duty. 2 blk/CU x 4 waves = 8 waves/CU, ~60-120 KB
// in flight per CU >> 9.2 KB BDP. Target: 192.6 MB @ ~6 TB/s ~= 31-35 us.

#define TPB 256
#define WPB 4                         // waves per block
#define WCELLS 64                     // cells per wave-tile (1 cell/lane)
#define WB (WCELLS * 120)             // 7680 B per array per wave-tile
#define SLICE (2 * WB)                // 15360 B wave-private LDS slice
#define R_TOTAL (16384 * 7 * 7)       // 802816 cells
#define NTILES (R_TOTAL / WCELLS)     // 12544 wave-tiles
#define GRID 512                      // 2 blocks/CU
#define NWAVES (GRID * WPB)           // 2048 waves; 6-7 tiles per wave

__global__ __launch_bounds__(TPB, 2) void yolo_loss_kernel(
    const float* __restrict__ pred, const float* __restrict__ target,
    float* __restrict__ out)
{
    __shared__ __align__(16) unsigned char smem[WPB * SLICE];  // 61440 B
    __shared__ float red[WPB];

    const int widx = threadIdx.x >> 6;
    const int lane = threadIdx.x & 63;
    unsigned char* slice = smem + widx * SLICE;

    // staging registers: per-lane 120 B per array = 7x float4 + 1x float2
    float4 vp[7], vt[7];
    float2 wp, wt;

    float sum = 0.0f;
    size_t t = (size_t)blockIdx.x * WPB + widx;

    // prologue load of first tile
    {
        const char* gp = (const char*)pred + t * (size_t)WB;
        const char* gt = (const char*)target + t * (size_t)WB;
        #pragma unroll
        for (int i = 0; i < 7; i++) vp[i] = *(const float4*)(gp + i * 1024 + lane * 16);
        wp = *(const float2*)(gp + 7168 + lane * 8);
        #pragma unroll
        for (int i = 0; i < 7; i++) vt[i] = *(const float4*)(gt + i * 1024 + lane * 16);
        wt = *(const float2*)(gt + 7168 + lane * 8);
    }

    for (;;) {
        // ---- store current tile regs -> wave-private LDS slice ----
        // (compiler inserts counted vmcnt waits for the pending loads)
        #pragma unroll
        for (int i = 0; i < 7; i++) *(float4*)(slice + i * 1024 + lane * 16) = vp[i];
        *(float2*)(slice + 7168 + lane * 8) = wp;
        #pragma unroll
        for (int i = 0; i < 7; i++) *(float4*)(slice + WB + i * 1024 + lane * 16) = vt[i];
        *(float2*)(slice + WB + 7168 + lane * 8) = wt;

        // ---- prefetch next tile: in flight across the compute below ----
        const size_t tn = t + NWAVES;
        const bool more = (tn < NTILES);
        if (more) {
            const char* gp = (const char*)pred + tn * (size_t)WB;
            const char* gt = (const char*)target + tn * (size_t)WB;
            #pragma unroll
            for (int i = 0; i < 7; i++) vp[i] = *(const float4*)(gp + i * 1024 + lane * 16);
            wp = *(const float2*)(gp + 7168 + lane * 8);
            #pragma unroll
            for (int i = 0; i < 7; i++) vt[i] = *(const float4*)(gt + i * 1024 + lane * 16);
            wt = *(const float2*)(gt + 7168 + lane * 8);
        }

        // ---- compute current tile from LDS (lane owns one cell) ----
        // cell stride 30 floats -> bank (lane*30)%32: 2 lanes/bank = free (m136)
        const float* pf = (const float*)(slice) + lane * 30;
        const float* tf = (const float*)(slice + WB) + lane * 30;

        const float t4 = tf[4];
        if (t4 == 0.0f) {
            // noobj: 0.5 * sum over conf_loc=[4,6] of (p-t)^2
            float d4 = pf[4] - t4;
            float d6 = pf[6] - tf[6];
            sum += 0.5f * (d4 * d4 + d6 * d6);
        } else if (t4 == 1.0f) {
            // target box -> xyxy (mirror reference float op order)
            float tx1 = tf[0] - tf[2] * 0.5f, ty1 = tf[1] - tf[3] * 0.5f;
            float tx2 = tf[0] + tf[2] * 0.5f, ty2 = tf[1] + tf[3] * 0.5f;
            float area2 = (tx2 - tx1) * (ty2 - ty1);

            // box 0
            float ax1 = pf[0] - pf[2] * 0.5f, ay1 = pf[1] - pf[3] * 0.5f;
            float ax2 = pf[0] + pf[2] * 0.5f, ay2 = pf[1] + pf[3] * 0.5f;
            float w0 = fmaxf(fminf(ax2, tx2) - fmaxf(ax1, tx1), 0.0f);
            float h0 = fmaxf(fminf(ay2, ty2) - fmaxf(ay1, ty1), 0.0f);
            float inter0 = w0 * h0;
            float uni0 = (ax2 - ax1) * (ay2 - ay1) + area2 - inter0;
            float iou0 = (uni0 > 0.0f) ? (inter0 / uni0) : 0.0f;

            // box 1
            float bx1 = pf[5] - pf[7] * 0.5f, by1 = pf[6] - pf[8] * 0.5f;
            float bx2 = pf[5] + pf[7] * 0.5f, by2 = pf[6] + pf[8] * 0.5f;
            float w1 = fmaxf(fminf(bx2, tx2) - fmaxf(bx1, tx1), 0.0f);
            float h1 = fmaxf(fminf(by2, ty2) - fmaxf(by1, ty1), 0.0f);
            float inter1 = w1 * h1;
            float uni1 = (bx2 - bx1) * (by2 - by1) + area2 - inter1;
            float iou1 = (uni1 > 0.0f) ? (inter1 / uni1) : 0.0f;

            // argmax over 2 -> first max index on ties
            bool j1 = (iou1 > iou0);
            float max_iou = fmaxf(iou0, iou1);
            // responsible box via per-element select (no dynamic indexing)
            float r0 = j1 ? pf[5] : pf[0];
            float r1 = j1 ? pf[6] : pf[1];
            float r2 = j1 ? pf[7] : pf[2];
            float r3 = j1 ? pf[8] : pf[3];
            float r4 = j1 ? pf[9] : pf[4];

            float dx = r0 - tf[0];
            float dy = r1 - tf[1];
            float sw = sqrtf(fmaxf(r2, 0.0f)) - sqrtf(fmaxf(tf[2], 0.0f));
            float sh = sqrtf(fmaxf(r3, 0.0f)) - sqrtf(fmaxf(tf[3], 0.0f));
            float coord = dx * dx + dy * dy + sw * sw + sh * sh;
            float dc = r4 - max_iou;

            float cls = 0.0f;
            #pragma unroll
            for (int k = 10; k < 30; k++) {
                float d = pf[k] - tf[k];
                cls += d * d;
            }
            sum += 5.0f * coord + dc * dc + cls;
        }
        // (t4 guaranteed in {0,1} by setup; other values contribute 0, matching ref)

        if (!more) break;
        t = tn;
    }

    // ---- reduce: wave-64 shfl, 4 partials via LDS, one atomic/block ----
    #pragma unroll
    for (int off = 32; off > 0; off >>= 1)
        sum += __shfl_down(sum, off, 64);
    if (lane == 0) red[widx] = sum;
    __syncthreads();
    if (threadIdx.x == 0) {
        float s = red[0] + red[1] + red[2] + red[3];
        atomicAdd(out, s * (1.0f / 16384.0f));
    }
}

extern "C" void kernel_launch(void* const* d_in, const int* in_sizes, int n_in,
                              void* d_out, int out_size, void* d_ws, size_t ws_size,
                              hipStream_t stream) {
    const float* pred = (const float*)d_in[0];
    const float* target = (const float*)d_in[1];
    float* out = (float*)d_out;
    // d_out is poisoned with 0xAA before every launch; we accumulate into it.
    hipMemsetAsync(out, 0, sizeof(float), stream);
    yolo_loss_kernel<<<GRID, TPB, 0, stream>>>(pred, target, out);
}

// Round 4
// 206.600 us; speedup vs baseline: 1.1276x; 1.1276x over previous
//
#include <hip/hip_runtime.h>

// YOLO loss, forward only. pred/target: (16384, 7, 7, 30) fp32, out: scalar fp32.
// S=7, B=2, CLS=20, N=30, LAMBDA_COORD=5, LAMBDA_NOOBJ=0.5, BATCH=16384.
// NOTE: reference conf_loc = arange(B)*B+4 = [4,6] (not [4,9]) — mirrored here.
//
// R5: register-direct float4 PAIR kernel. History:
//   R1 register-direct float2, stride 120B: 75us (8 useful B/lane-request)
//   R2 global_load_lds DMA, 1 wave/blk:     75us (DMA completion-rate bound)
//   R3 reg-staged + LDS + barrier:        73.5us (2 blocks/CU latency-phased)
//   R4 barrier-free LDS pipeline:          100us (conditional prefetch reg
//      arrays -> SCRATCH: WRITE_SIZE 0.1->168 MB. Never again.)
// Common failure: delivered BW stuck at ~2.6 TB/s because no variant kept
// enough USEFUL bytes in flight per CU continuously. R5: two cells per
// thread = 240 B = 15 float4 per array (240*i is 16B-aligned), 30 straight-
// line dwordx4 loads per thread, no LDS tile, no barriers, no loop-carried
// register state. Occupancy VGPR-capped only (~8-12 waves/CU -> 240-360 KB
// in flight per CU). All data indices compile-time constants (macros).

typedef float v4f __attribute__((ext_vector_type(4)));

#define TPB 256
#define R_TOTAL (16384 * 7 * 7)       // 802816 cells
#define NPAIRS (R_TOTAL / 2)          // 401408 pairs
#define GRID (NPAIRS / TPB)           // 1568 blocks

// element j (0..59) of the pair record held in a v4f[15] array; j must be a
// compile-time constant so every access is a register, never scratch.
#define EL(a, j) (a[(j) >> 2][(j) & 3])

// loss for one cell at float offset OFS (0 or 30) within the pair record.
#define CELL_LOSS(OFS) do {                                                   \
    const float t4v = EL(t4, (OFS) + 4);                                      \
    if (t4v == 0.0f) {                                                        \
        float d4 = EL(p4, (OFS) + 4) - t4v;                                   \
        float d6 = EL(p4, (OFS) + 6) - EL(t4, (OFS) + 6);                     \
        sum += 0.5f * (d4 * d4 + d6 * d6);                                    \
    } else if (t4v == 1.0f) {                                                 \
        float tx1 = EL(t4,(OFS)+0) - EL(t4,(OFS)+2) * 0.5f;                   \
        float ty1 = EL(t4,(OFS)+1) - EL(t4,(OFS)+3) * 0.5f;                   \
        float tx2 = EL(t4,(OFS)+0) + EL(t4,(OFS)+2) * 0.5f;                   \
        float ty2 = EL(t4,(OFS)+1) + EL(t4,(OFS)+3) * 0.5f;                   \
        float area2 = (tx2 - tx1) * (ty2 - ty1);                              \
        float ax1 = EL(p4,(OFS)+0) - EL(p4,(OFS)+2) * 0.5f;                   \
        float ay1 = EL(p4,(OFS)+1) - EL(p4,(OFS)+3) * 0.5f;                   \
        float ax2 = EL(p4,(OFS)+0) + EL(p4,(OFS)+2) * 0.5f;                   \
        float ay2 = EL(p4,(OFS)+1) + EL(p4,(OFS)+3) * 0.5f;                   \
        float w0 = fmaxf(fminf(ax2, tx2) - fmaxf(ax1, tx1), 0.0f);            \
        float h0 = fmaxf(fminf(ay2, ty2) - fmaxf(ay1, ty1), 0.0f);            \
        float inter0 = w0 * h0;                                               \
        float uni0 = (ax2 - ax1) * (ay2 - ay1) + area2 - inter0;              \
        float iou0 = (uni0 > 0.0f) ? (inter0 / uni0) : 0.0f;                  \
        float bx1 = EL(p4,(OFS)+5) - EL(p4,(OFS)+7) * 0.5f;                   \
        float by1 = EL(p4,(OFS)+6) - EL(p4,(OFS)+8) * 0.5f;                   \
        float bx2 = EL(p4,(OFS)+5) + EL(p4,(OFS)+7) * 0.5f;                   \
        float by2 = EL(p4,(OFS)+6) + EL(p4,(OFS)+8) * 0.5f;                   \
        float w1 = fmaxf(fminf(bx2, tx2) - fmaxf(bx1, tx1), 0.0f);            \
        float h1 = fmaxf(fminf(by2, ty2) - fmaxf(by1, ty1), 0.0f);            \
        float inter1 = w1 * h1;                                               \
        float uni1 = (bx2 - bx1) * (by2 - by1) + area2 - inter1;              \
        float iou1 = (uni1 > 0.0f) ? (inter1 / uni1) : 0.0f;                  \
        bool j1 = (iou1 > iou0);                                              \
        float max_iou = fmaxf(iou0, iou1);                                    \
        float r0 = j1 ? EL(p4,(OFS)+5) : EL(p4,(OFS)+0);                      \
        float r1 = j1 ? EL(p4,(OFS)+6) : EL(p4,(OFS)+1);                      \
        float r2 = j1 ? EL(p4,(OFS)+7) : EL(p4,(OFS)+2);                      \
        float r3 = j1 ? EL(p4,(OFS)+8) : EL(p4,(OFS)+3);                      \
        float r4 = j1 ? EL(p4,(OFS)+9) : EL(p4,(OFS)+4);                      \
        float dx = r0 - EL(t4,(OFS)+0);                                       \
        float dy = r1 - EL(t4,(OFS)+1);                                       \
        float sw = sqrtf(fmaxf(r2, 0.0f)) - sqrtf(fmaxf(EL(t4,(OFS)+2), 0.0f));\
        float sh = sqrtf(fmaxf(r3, 0.0f)) - sqrtf(fmaxf(EL(t4,(OFS)+3), 0.0f));\
        float coord = dx * dx + dy * dy + sw * sw + sh * sh;                  \
        float dc = r4 - max_iou;                                              \
        float cls = 0.0f;                                                     \
        _Pragma("unroll")                                                     \
        for (int k = 10; k < 30; k++) {                                       \
            float d = EL(p4,(OFS)+k) - EL(t4,(OFS)+k);                        \
            cls += d * d;                                                     \
        }                                                                     \
        sum += 5.0f * coord + dc * dc + cls;                                  \
    }                                                                         \
} while (0)
// (t4 guaranteed in {0,1} by setup; other values contribute 0, matching ref)

__global__ __launch_bounds__(TPB) void yolo_loss_kernel(
    const float* __restrict__ pred, const float* __restrict__ target,
    float* __restrict__ out)
{
    __shared__ float red[TPB / 64];

    const int tid = threadIdx.x;
    const size_t pair = (size_t)blockIdx.x * TPB + tid;

    // 30 straight-line dwordx4 loads, 16 useful bytes per lane-request,
    // every fetched byte consumed. No loop-carried register state.
    const v4f* gp = (const v4f*)(pred + pair * 60);
    const v4f* gt = (const v4f*)(target + pair * 60);
    v4f p4[15], t4[15];
    #pragma unroll
    for (int k = 0; k < 15; k++) p4[k] = gp[k];
    #pragma unroll
    for (int k = 0; k < 15; k++) t4[k] = gt[k];

    float sum = 0.0f;
    CELL_LOSS(0);    // cell A: floats [0,30)
    CELL_LOSS(30);   // cell B: floats [30,60)

    // wave-64 shfl reduction, 4 partials via LDS, one atomic per block
    #pragma unroll
    for (int off = 32; off > 0; off >>= 1)
        sum += __shfl_down(sum, off, 64);
    if ((tid & 63) == 0) red[tid >> 6] = sum;
    __syncthreads();
    if (tid == 0) {
        float s = red[0] + red[1] + red[2] + red[3];
        atomicAdd(out, s * (1.0f / 16384.0f));
    }
}

extern "C" void kernel_launch(void* const* d_in, const int* in_sizes, int n_in,
                              void* d_out, int out_size, void* d_ws, size_t ws_size,
                              hipStream_t stream) {
    const float* pred = (const float*)d_in[0];
    const float* target = (const float*)d_in[1];
    float* out = (float*)d_out;
    // d_out is poisoned with 0xAA before every launch; we accumulate into it.
    hipMemsetAsync(out, 0, sizeof(float), stream);
    yolo_loss_kernel<<<GRID, TPB, 0, stream>>>(pred, target, out);
}